// Round 14
// baseline (292.966 us; speedup 1.0000x reference)
//
#include <hip/hip_runtime.h>
#include <cmath>

#define TT 500
#define NTOT 2048000       // T*B*C elements
#define WW 20

typedef _Float16 f16x8 __attribute__((ext_vector_type(8)));
typedef _Float16 f16x4 __attribute__((ext_vector_type(4)));
typedef float f32x4 __attribute__((ext_vector_type(4)));

#define C1SC 4.8828125e-4f          // 2^-11
#define C2SC 2.384185791015625e-7f  // 2^-22

// async global->LDS; LDS dest = wave-uniform base + lane*width
__device__ __forceinline__ void gload16(const _Float16* g, _Float16* l) {
    __builtin_amdgcn_global_load_lds(
        (const __attribute__((address_space(1))) unsigned int*)g,
        (__attribute__((address_space(3))) unsigned int*)l, 16, 0, 0);
}
__device__ __forceinline__ void gload16f(const float* g, float* l) {
    __builtin_amdgcn_global_load_lds(
        (const __attribute__((address_space(1))) unsigned int*)g,
        (__attribute__((address_space(3))) unsigned int*)l, 16, 0, 0);
}
__device__ __forceinline__ void gload4b(const unsigned char* g, unsigned char* l) {
    __builtin_amdgcn_global_load_lds(
        (const __attribute__((address_space(1))) unsigned int*)g,
        (__attribute__((address_space(3))) unsigned int*)l, 4, 0, 0);
}

// ---------------------------------------------------------------------------
// Split prep: all tensors -> 2-way scaled fp16 split (h0 + 2^-11*h1).
// ---------------------------------------------------------------------------
__global__ __launch_bounds__(256) void prep_split_k(
    const float* __restrict__ x, const float* __restrict__ wq,
    const float* __restrict__ wk, const float* __restrict__ wv,
    const float* __restrict__ wm, const float* __restrict__ wp,
    _Float16* __restrict__ X0, _Float16* __restrict__ X1,
    _Float16* __restrict__ Q0, _Float16* __restrict__ Q1,
    _Float16* __restrict__ M0, _Float16* __restrict__ M1,
    _Float16* __restrict__ P0, _Float16* __restrict__ P1)
{
    int gid = blockIdx.x * 256 + threadIdx.x;
    const float* src;
    _Float16 *d0, *d1;
    size_t si, di;
    if (gid < 512000) {
        src = x; d0 = X0; d1 = X1; si = di = (size_t)gid * 4;
    } else if (gid < 708608) {
        int g = gid - 512000;                      // 0..196607 (3 x 65536)
        int s3 = g >> 16;
        src = (s3 == 0) ? wq : ((s3 == 1) ? wk : wv);
        d0 = Q0; d1 = Q1;
        si = (size_t)(g & 65535) * 4;
        di = (size_t)g * 4;
    } else if (gid < 774144) {
        int g = gid - 708608;
        src = wm; d0 = M0; d1 = M1; si = di = (size_t)g * 4;
    } else {
        int g = gid - 774144;
        src = wp; d0 = P0; d1 = P1; si = di = (size_t)g * 4;
    }
    float4 v = *(const float4*)(src + si);
    float f[4] = {v.x, v.y, v.z, v.w};
    f16x4 a, b;
#pragma unroll
    for (int i = 0; i < 4; ++i) {
        _Float16 h0 = (_Float16)f[i];
        float r1 = f[i] - (float)h0;              // exact (Sterbenz)
        _Float16 h1 = (_Float16)(r1 * 2048.0f);   // exact pow2 scale
        a[i] = h0; b[i] = h1;
    }
    *(f16x4*)(d0 + di) = a;
    *(f16x4*)(d1 + di) = b;
}

// ---------------------------------------------------------------------------
// QKV GEMM via MFMA: x 2-split, W 2-split, 3 acc banks:
//   acc0 += a0b0 ; acc1 += a0b1 + a1b0 ; acc2 += a1b1
//   result = acc0 + 2^-11*acc1 + 2^-22*acc2   (error ~2x2^-22)
// Double-buffered gload_lds staging, BM=64,BN=128,BK=32, 4 waves (wave tile
// 32x64), grid 768, 48 KB LDS -> 3 blocks/CU.
// ---------------------------------------------------------------------------
__global__ __launch_bounds__(256) void gemm_f16s3_k(
    const _Float16* __restrict__ X0, const _Float16* __restrict__ X1,
    const _Float16* __restrict__ B0g, const _Float16* __restrict__ B1g,
    float* __restrict__ out, float* __restrict__ colpart, int M)
{
    // per buffer (12288 halfs): A0@0 A1@2048 | B0@4096 B1@8192
    __shared__ __align__(16) _Float16 sA[24576];   // 48 KB, 2 buffers
    int tid = threadIdx.x;
    int bid = blockIdx.x;
    int xcd = bid & 7;
    int j = bid >> 3;                 // 0..95
    int mblk = (xcd << 3) | (j & 7);  // 0..63
    int nblk = j >> 3;                // 0..11
    int mBase = mblk * 64;
    int nBase = nblk * 128;
    int wv = tid >> 6;
    int lane = tid & 63;
    int wr = wv >> 1, wc = wv & 1;
    int lg = lane >> 4, l16 = lane & 15;

    int subrow = lane >> 2;            // 0..15
    int s4 = lane & 3;                 // global k-chunk slot before swizzle
    int rA = (wv << 4) + subrow;       // local row 0..63
    int sl8 = (s4 ^ ((rA >> 1) & 3)) * 8;   // swizzled slot offset (halfs)
    int mA = mBase + rA; if (mA >= M) mA = 0;   // clamp; masked in epilogue
    const _Float16* gA0 = X0 + (size_t)mA * 512 + sl8;
    const _Float16* gA1 = X1 + (size_t)mA * 512 + sl8;
    const _Float16* gB00 = B0g + (size_t)(nBase + rA) * 512 + sl8;
    const _Float16* gB01 = B0g + (size_t)(nBase + 64 + rA) * 512 + sl8;
    const _Float16* gB10 = B1g + (size_t)(nBase + rA) * 512 + sl8;
    const _Float16* gB11 = B1g + (size_t)(nBase + 64 + rA) * 512 + sl8;
    int wb = wv << 9;                  // wave LDS base (halfs)
    _Float16* lA0 = sA + wb;
    _Float16* lA1 = sA + 2048 + wb;
    _Float16* lB00 = sA + 4096 + wb;
    _Float16* lB01 = sA + 6144 + wb;
    _Float16* lB10 = sA + 8192 + wb;
    _Float16* lB11 = sA + 10240 + wb;

    auto stage = [&](int kt, int off) {
        gload16(gA0 + kt, lA0 + off);
        gload16(gA1 + kt, lA1 + off);
        gload16(gB00 + kt, lB00 + off);
        gload16(gB01 + kt, lB01 + off);
        gload16(gB10 + kt, lB10 + off);
        gload16(gB11 + kt, lB11 + off);
    };

    int sd = (lg ^ ((l16 >> 1) & 3)) * 8;   // swizzled read slot (halfs)

    f32x4 acc0[2][4] = {}, acc1[2][4] = {}, acc2[2][4] = {};

    stage(0, 0);
    __syncthreads();                   // buf0 ready
    int cur = 0;
    for (int kt = 0; kt < 512; kt += 32) {
        int coff = cur * 12288;
        if (kt + 32 < 512) stage(kt + 32, 12288 - coff);   // prefetch buf^1
        f16x8 a0f[2], a1f[2];
#pragma unroll
        for (int i = 0; i < 2; ++i) {
            int off = (wr * 32 + i * 16 + l16) * 32 + sd + coff;
            a0f[i] = *(const f16x8*)&sA[off];
            a1f[i] = *(const f16x8*)&sA[2048 + off];
        }
#pragma unroll
        for (int jj = 0; jj < 4; ++jj) {
            int boff = 4096 + (wc * 64 + jj * 16 + l16) * 32 + sd + coff;
            f16x8 b0f = *(const f16x8*)&sA[boff];
            f16x8 b1f = *(const f16x8*)&sA[4096 + boff];
#pragma unroll
            for (int i = 0; i < 2; ++i) {
                acc0[i][jj] = __builtin_amdgcn_mfma_f32_16x16x32_f16(a0f[i], b0f, acc0[i][jj], 0, 0, 0);
                acc1[i][jj] = __builtin_amdgcn_mfma_f32_16x16x32_f16(a0f[i], b1f, acc1[i][jj], 0, 0, 0);
                acc1[i][jj] = __builtin_amdgcn_mfma_f32_16x16x32_f16(a1f[i], b0f, acc1[i][jj], 0, 0, 0);
                acc2[i][jj] = __builtin_amdgcn_mfma_f32_16x16x32_f16(a1f[i], b1f, acc2[i][jj], 0, 0, 0);
            }
        }
        __syncthreads();               // drains prefetch vmcnt + lgkm; swap
        cur ^= 1;
    }
#pragma unroll
    for (int i = 0; i < 2; ++i)
#pragma unroll
        for (int jj = 0; jj < 4; ++jj)
#pragma unroll
            for (int r = 0; r < 4; ++r)
                acc0[i][jj][r] = fmaf(C2SC, acc2[i][jj][r],
                                      fmaf(C1SC, acc1[i][jj][r], acc0[i][jj][r]));
    // fused per-column stats; rows >= M masked to 0.
    float* red = (float*)sA;   // [2][128][2]
#pragma unroll
    for (int jj = 0; jj < 4; ++jj) {
        float s = 0.f, q = 0.f;
#pragma unroll
        for (int i = 0; i < 2; ++i)
#pragma unroll
            for (int r = 0; r < 4; ++r) {
                int mrow = mBase + wr * 32 + i * 16 + lg * 4 + r;
                float v = (mrow < M) ? acc0[i][jj][r] : 0.f;
                s += v; q = fmaf(v, v, q);
            }
        s += __shfl_xor(s, 16, 64); s += __shfl_xor(s, 32, 64);
        q += __shfl_xor(q, 16, 64); q += __shfl_xor(q, 32, 64);
        if (lane < 16) {
            int col = wc * 64 + jj * 16 + lane;
            red[(wr * 128 + col) * 2 + 0] = s;
            red[(wr * 128 + col) * 2 + 1] = q;
        }
    }
    __syncthreads();
    if (tid < 128) {
        float ss = red[tid * 2 + 0] + red[(128 + tid) * 2 + 0];
        float qq = red[tid * 2 + 1] + red[(128 + tid) * 2 + 1];
        colpart[((size_t)mblk * 1536 + nBase + tid) * 2 + 0] = ss;
        colpart[((size_t)mblk * 1536 + nBase + tid) * 2 + 1] = qq;
    }
    int wsel = nBase >> 9;
    int col0 = nBase & 511;
    float* outp = out + (size_t)wsel * NTOT;
#pragma unroll
    for (int i = 0; i < 2; ++i) {
        int m0 = mBase + wr * 32 + i * 16 + lg * 4;
#pragma unroll
        for (int jj = 0; jj < 4; ++jj) {
            int cc = col0 + wc * 64 + jj * 16 + l16;
#pragma unroll
            for (int r = 0; r < 4; ++r) {
                int m = m0 + r;
                if (m < M) outp[(size_t)m * 512 + cc] = acc0[i][jj][r];
            }
        }
    }
}

// ---------------------------------------------------------------------------
// Spike GEMM via MFMA: A fp16 spikes (exact), W 2-split, 2 acc banks.
// TRI-buffered counted-vmcnt pipeline (vmcnt(3) steady). BM=64,BN=64,
// grid 512, 36 KB LDS.
// ---------------------------------------------------------------------------
__global__ __launch_bounds__(256) void gemm_hs3_k(
    const _Float16* __restrict__ Ah,
    const _Float16* __restrict__ B0g, const _Float16* __restrict__ B1g,
    float* __restrict__ out, float* __restrict__ colpart, int M)
{
    // per buffer (6144 halfs): A@0 B0@2048 B1@4096
    __shared__ __align__(16) _Float16 sH[18432];   // 36 KB, 3 buffers
    int tid = threadIdx.x;
    int bid = blockIdx.x;
    int xcd = bid & 7;
    int j = bid >> 3;                 // 0..63
    int mblk = (xcd << 3) | (j & 7);  // 0..63
    int nblk = j >> 3;                // 0..7
    int mBase = mblk * 64;
    int col0 = nblk * 64;
    int wv = tid >> 6;
    int lane = tid & 63;
    int wr = wv >> 1, wc = wv & 1;
    int lg = lane >> 4, l16 = lane & 15;

    int subrow = lane >> 2;
    int s4 = lane & 3;
    int rA = (wv << 4) + subrow;       // 0..63
    int sl8 = (s4 ^ ((rA >> 1) & 3)) * 8;
    int mA = mBase + rA; if (mA >= M) mA = 0;
    const _Float16* gA  = Ah  + (size_t)mA * 512 + sl8;
    const _Float16* gB0 = B0g + (size_t)(col0 + rA) * 512 + sl8;
    const _Float16* gB1 = B1g + (size_t)(col0 + rA) * 512 + sl8;
    int wb = wv << 9;

    auto stage = [&](int kt, int off) {
        gload16(gA + kt, sH + off + wb);
        gload16(gB0 + kt, sH + off + 2048 + wb);
        gload16(gB1 + kt, sH + off + 4096 + wb);
    };

    int sd = (lg ^ ((l16 >> 1) & 3)) * 8;

    f32x4 acc0[2][2] = {}, acc1[2][2] = {};

    auto compute = [&](int coff) {
        f16x8 af[2];
#pragma unroll
        for (int i = 0; i < 2; ++i)
            af[i] = *(const f16x8*)&sH[(wr * 32 + i * 16 + l16) * 32 + sd + coff];
#pragma unroll
        for (int jj = 0; jj < 2; ++jj) {
            int boff = 2048 + (wc * 32 + jj * 16 + l16) * 32 + sd + coff;
            f16x8 b0f = *(const f16x8*)&sH[boff];
            f16x8 b1f = *(const f16x8*)&sH[2048 + boff];
#pragma unroll
            for (int i = 0; i < 2; ++i) {
                acc0[i][jj] = __builtin_amdgcn_mfma_f32_16x16x32_f16(af[i], b0f, acc0[i][jj], 0, 0, 0);
                acc1[i][jj] = __builtin_amdgcn_mfma_f32_16x16x32_f16(af[i], b1f, acc1[i][jj], 0, 0, 0);
            }
        }
    };

    stage(0, 0);
    stage(32, 6144);
    int offC = 0, offS = 12288;
    for (int n = 0; n < 14; ++n) {
        asm volatile("s_waitcnt vmcnt(3)" ::: "memory");
        __builtin_amdgcn_s_barrier();
        stage((n + 2) * 32, offS);
        compute(offC);
        offC += 6144; if (offC == 18432) offC = 0;
        offS += 6144; if (offS == 18432) offS = 0;
    }
    asm volatile("s_waitcnt vmcnt(3)" ::: "memory");
    __builtin_amdgcn_s_barrier();
    compute(offC);
    offC += 6144; if (offC == 18432) offC = 0;
    asm volatile("s_waitcnt vmcnt(0)" ::: "memory");
    __builtin_amdgcn_s_barrier();
    compute(offC);
    __syncthreads();

#pragma unroll
    for (int i = 0; i < 2; ++i)
#pragma unroll
        for (int jj = 0; jj < 2; ++jj)
#pragma unroll
            for (int r = 0; r < 4; ++r)
                acc0[i][jj][r] = fmaf(C1SC, acc1[i][jj][r], acc0[i][jj][r]);
    float* red = (float*)sH;   // [2][64][2]
#pragma unroll
    for (int jj = 0; jj < 2; ++jj) {
        float s = 0.f, q = 0.f;
#pragma unroll
        for (int i = 0; i < 2; ++i)
#pragma unroll
            for (int r = 0; r < 4; ++r) {
                int mrow = mBase + wr * 32 + i * 16 + lg * 4 + r;
                float v = (mrow < M) ? acc0[i][jj][r] : 0.f;
                s += v; q = fmaf(v, v, q);
            }
        s += __shfl_xor(s, 16, 64); s += __shfl_xor(s, 32, 64);
        q += __shfl_xor(q, 16, 64); q += __shfl_xor(q, 32, 64);
        if (lane < 16) {
            int col = wc * 32 + jj * 16 + lane;
            red[(wr * 64 + col) * 2 + 0] = s;
            red[(wr * 64 + col) * 2 + 1] = q;
        }
    }
    __syncthreads();
    if (tid < 64) {
        float ss = red[tid * 2 + 0] + red[(64 + tid) * 2 + 0];
        float qq = red[tid * 2 + 1] + red[(64 + tid) * 2 + 1];
        colpart[((size_t)mblk * 512 + col0 + tid) * 2 + 0] = ss;
        colpart[((size_t)mblk * 512 + col0 + tid) * 2 + 1] = qq;
    }
#pragma unroll
    for (int i = 0; i < 2; ++i) {
        int m0 = mBase + wr * 32 + i * 16 + lg * 4;
#pragma unroll
        for (int jj = 0; jj < 2; ++jj) {
            int cc = col0 + wc * 32 + jj * 16 + l16;
#pragma unroll
            for (int r = 0; r < 4; ++r) {
                int m = m0 + r;
                if (m < M) out[(size_t)m * 512 + cc] = acc0[i][jj][r];
            }
        }
    }
}

// ---------------------------------------------------------------------------
// Time-segmented BN+LIF with INLINE stats finalize (f64, identical math).
// ---------------------------------------------------------------------------
__global__ __launch_bounds__(256) void lif_seg_k(
    const float* __restrict__ pre, const float* __restrict__ colpart, int CT, int chunks,
    const float* __restrict__ gamma, const float* __restrict__ beta,
    float* __restrict__ outF, unsigned char* __restrict__ outB,
    _Float16* __restrict__ outH, int segLen, int warm)
{
    int gid = blockIdx.x * 256 + threadIdx.x;
    int tensor = gid >> 12;
    int bc = gid & 4095;
    int ch = (tensor << 9) | (bc & 511);
    double s = 0.0, s2 = 0.0;
    for (int k = 0; k < chunks; ++k) {
        s  += (double)colpart[((size_t)k * CT + ch) * 2 + 0];
        s2 += (double)colpart[((size_t)k * CT + ch) * 2 + 1];
    }
    double mean = s / 4000.0;
    double var = s2 / 4000.0 - mean * mean;
    double scd = (double)gamma[ch] / sqrt(var + 1e-5);
    float sc = (float)scd;
    float sh = (float)((double)beta[ch] - mean * scd);
    const float* q0 = pre + (size_t)tensor * NTOT + bc;
    float* oF = outF ? outF + (size_t)tensor * NTOT + bc : nullptr;
    unsigned char* oB = outB ? outB + (size_t)tensor * NTOT + bc : nullptr;
    _Float16* oH = outH ? outH + (size_t)tensor * NTOT + bc : nullptr;
    int t0 = blockIdx.y * segLen;
    int twarm = (t0 - warm > 0) ? (t0 - warm) : 0;
    int tend = (t0 + segLen < TT) ? (t0 + segLen) : TT;
    float v = 0.f;
    float b0[8];
#pragma unroll
    for (int j = 0; j < 8; ++j) {
        int tt = twarm + j;
        b0[j] = (tt < tend) ? q0[(size_t)tt * 4096] : 0.f;
    }
    for (int t = twarm; t < tend; t += 8) {
        float n0[8];
#pragma unroll
        for (int j = 0; j < 8; ++j) {
            int tt = t + 8 + j;
            n0[j] = (tt < tend) ? q0[(size_t)tt * 4096] : 0.f;
        }
#pragma unroll
        for (int j = 0; j < 8; ++j) {
            int tc = t + j;
            if (tc >= tend) break;
            float bnx = fmaf(b0[j], sc, sh);
            float h = fmaf(0.5f, v, bnx);
            float sp = (h >= 1.f) ? 1.f : 0.f;
            v = (h >= 1.f) ? 0.f : h;
            if (tc >= t0) {
                if (oB)      oB[(size_t)tc * 4096] = (unsigned char)sp;
                else if (oH) oH[(size_t)tc * 4096] = (_Float16)sp;
                else         oF[(size_t)tc * 4096] = sp;
            }
        }
#pragma unroll
        for (int j = 0; j < 8; ++j) b0[j] = n0[j];
    }
}

// ---------------------------------------------------------------------------
// FUSED attention kernel: blocks 0..255 = KtV partials; 256..1279 = local
// banded attention. Bodies byte-identical; shared 57 KB LDS arena.
// ---------------------------------------------------------------------------
__global__ __launch_bounds__(256) void attn_fused_k(
    const unsigned char* __restrict__ qspk, const unsigned char* __restrict__ kspk,
    const unsigned char* __restrict__ vspk, float* __restrict__ lpre,
    float* __restrict__ part, float lscale)
{
    __shared__ __align__(16) float smem[14272];   // 57,088 B arena
    int tid = threadIdx.x;
    int bid = blockIdx.x;

    if (bid < 256) {
        // ---------------- ktv_part path ----------------
        float (*kb)[64] = (float(*)[64])smem;          // [16][64]
        float (*vb)[64] = (float(*)[64])(smem + 1024); // [16][64]
        int bh = bid & 63;
        int seg = bid >> 6;
        int t0p = seg * 125, t1p = t0p + 125;
        int b = bh >> 3, h = bh & 7;
        int d1b = (tid >> 4) * 4, d2b = (tid & 15) * 4;
        size_t cb = (size_t)b * 512 + h * 64;
        int sRow = tid >> 4;
        int sD = (tid & 15) * 4;
        float acc[4][4] = {};
        uchar4 pk, pv;
        auto preload = [&](int tt) {
            int t = tt + sRow;
            if (t < t1p) {
                pk = *(const uchar4*)(kspk + (size_t)t * 4096 + cb + sD);
                pv = *(const uchar4*)(vspk + (size_t)t * 4096 + cb + sD);
            } else {
                pk = make_uchar4(0, 0, 0, 0); pv = make_uchar4(0, 0, 0, 0);
            }
        };
        preload(t0p);
        for (int tt = t0p; tt < t1p; tt += 16) {
            __syncthreads();
            kb[sRow][sD + 0] = (float)pk.x; kb[sRow][sD + 1] = (float)pk.y;
            kb[sRow][sD + 2] = (float)pk.z; kb[sRow][sD + 3] = (float)pk.w;
            vb[sRow][sD + 0] = (float)pv.x; vb[sRow][sD + 1] = (float)pv.y;
            vb[sRow][sD + 2] = (float)pv.z; vb[sRow][sD + 3] = (float)pv.w;
            __syncthreads();
            preload(tt + 16);
#pragma unroll
            for (int tl = 0; tl < 16; ++tl) {
                float4 k4 = *(const float4*)&kb[tl][d1b];
                float4 v4 = *(const float4*)&vb[tl][d2b];
                float ka[4] = {k4.x, k4.y, k4.z, k4.w};
                float va[4] = {v4.x, v4.y, v4.z, v4.w};
#pragma unroll
                for (int i = 0; i < 4; ++i)
#pragma unroll
                    for (int j2 = 0; j2 < 4; ++j2)
                        acc[i][j2] = fmaf(ka[i], va[j2], acc[i][j2]);
            }
        }
        size_t ob = ((size_t)seg * 64 + bh) * 4096;
#pragma unroll
        for (int i = 0; i < 4; ++i)
            *(float4*)(part + ob + (size_t)(d1b + i) * 64 + d2b) =
                make_float4(acc[i][0], acc[i][1], acc[i][2], acc[i][3]);
        return;
    }

    // ---------------- local_k path ----------------
    int lb = bid - 256;
    int t0 = (lb >> 6) * 32;
    int bh = lb & 63;
    float (*qs)[68] = (float(*)[68])smem;            // [32][68]
    float (*ks)[68] = (float(*)[68])(smem + 2176);   // [72][68]
    float (*vs)[68] = (float(*)[68])(smem + 7072);   // [72][68]
    float (*sm)[72] = (float(*)[72])(smem + 11968);  // [32][72]
    int b = bh >> 3, h = bh & 7;
    size_t cb = (size_t)b * 512 + h * 64;

    for (int i = tid; i < 512; i += 256) {
        int r = i >> 4, d4 = (i & 15) * 4;
        int t = t0 + r;
        if (t < TT) {
            uchar4 u = *(const uchar4*)(qspk + (size_t)t * 4096 + cb + d4);
            qs[r][d4 + 0] = (float)u.x; qs[r][d4 + 1] = (float)u.y;
            qs[r][d4 + 2] = (float)u.z; qs[r][d4 + 3] = (float)u.w;
        } else {
            qs[r][d4 + 0] = 0.f; qs[r][d4 + 1] = 0.f; qs[r][d4 + 2] = 0.f; qs[r][d4 + 3] = 0.f;
        }
    }
    for (int i = tid; i < 1152; i += 256) {
        int r = i >> 4, d4 = (i & 15) * 4;
        int u_ = t0 - WW + r;
        if (u_ >= 0 && u_ < TT) {
            uchar4 uk = *(const uchar4*)(kspk + (size_t)u_ * 4096 + cb + d4);
            uchar4 uv = *(const uchar4*)(vspk + (size_t)u_ * 4096 + cb + d4);
            ks[r][d4 + 0] = (float)uk.x; ks[r][d4 + 1] = (float)uk.y;
            ks[r][d4 + 2] = (float)uk.z; ks[r][d4 + 3] = (float)uk.w;
            vs[r][d4 + 0] = (float)uv.x; vs[r][d4 + 1] = (float)uv.y;
            vs[r][d4 + 2] = (float)uv.z; vs[r][d4 + 3] = (float)uv.w;
        } else {
            ks[r][d4 + 0] = 0.f; ks[r][d4 + 1] = 0.f; ks[r][d4 + 2] = 0.f; ks[r][d4 + 3] = 0.f;
            vs[r][d4 + 0] = 0.f; vs[r][d4 + 1] = 0.f; vs[r][d4 + 2] = 0.f; vs[r][d4 + 3] = 0.f;
        }
    }
    __syncthreads();

    int tA = tid >> 3;
    int ug = tid & 7;
    float4 qreg[16];
#pragma unroll
    for (int i = 0; i < 16; ++i) qreg[i] = *(const float4*)&qs[tA][i * 4];
#pragma unroll
    for (int ui = 0; ui < 9; ++ui) {
        int u = ug + ui * 8;
        float acc = 0.f;
#pragma unroll
        for (int i = 0; i < 16; ++i) {
            float4 k4 = *(const float4*)&ks[u][i * 4];
            acc = fmaf(qreg[i].x, k4.x, acc);
            acc = fmaf(qreg[i].y, k4.y, acc);
            acc = fmaf(qreg[i].z, k4.z, acc);
            acc = fmaf(qreg[i].w, k4.w, acc);
        }
        sm[tA][u] = acc;
    }
    __syncthreads();

#pragma unroll
    for (int oi = 0; oi < 2; ++oi) {
        int idx = tid + oi * 256;
        int t = idx >> 4;
        int dg = (idx & 15) * 4;
        float4 acc = make_float4(0.f, 0.f, 0.f, 0.f);
        for (int o = 0; o < 41; ++o) {
            int u = t + o;
            float s = sm[t][u];
            float4 v4 = *(const float4*)&vs[u][dg];
            acc.x = fmaf(s, v4.x, acc.x);
            acc.y = fmaf(s, v4.y, acc.y);
            acc.z = fmaf(s, v4.z, acc.z);
            acc.w = fmaf(s, v4.w, acc.w);
        }
        int tg = t0 + t;
        if (tg < TT) {
            acc.x *= lscale; acc.y *= lscale; acc.z *= lscale; acc.w *= lscale;
            *(float4*)(lpre + (size_t)tg * 4096 + cb + dg) = acc;
        }
    }
}

// ---------------------------------------------------------------------------
// Global attention apply, t-tiled x10, float4 qs reads. Reads the 4 KtV
// t-quarter partials directly and sums ((p0+p1)+p2)+p3 — exactly the
// order the deleted ktv_reduce_k used -> bit-identical kv values.
// ---------------------------------------------------------------------------
__global__ __launch_bounds__(256) void gapply_t_k(
    const unsigned char* __restrict__ sq, const float* __restrict__ part,
    float* __restrict__ gpre, float gscale)
{
    __shared__ __align__(16) float qs[10][512];
    int tid = threadIdx.x;
    int t0 = blockIdx.x * 10;
    int b = blockIdx.y;
    for (int i = tid; i < 1280; i += 256) {
        int t = i >> 7;
        int c4 = (i & 127) * 4;
        uchar4 u = *(const uchar4*)(sq + (size_t)(t0 + t) * 4096 + b * 512 + c4);
        qs[t][c4 + 0] = (float)u.x; qs[t][c4 + 1] = (float)u.y;
        qs[t][c4 + 2] = (float)u.z; qs[t][c4 + 3] = (float)u.w;
    }
    __syncthreads();
#pragma unroll
    for (int half = 0; half < 2; ++half) {
        int c = tid + half * 256;
        int h = c >> 6, dcol = c & 63;
        const float* kt = part + ((size_t)(b * 8 + h) * 64) * 64 + dcol;
        float acc[10] = {};
        for (int d1b = 0; d1b < 64; d1b += 4) {
            float kv[4];
#pragma unroll
            for (int e = 0; e < 4; ++e) {
                size_t i0 = (size_t)(d1b + e) * 64;
                float pa = kt[i0];
                float pb = kt[262144 + i0];
                float pc = kt[2 * 262144 + i0];
                float pd = kt[3 * 262144 + i0];
                kv[e] = ((pa + pb) + pc) + pd;
            }
#pragma unroll
            for (int t = 0; t < 10; ++t) {
                float4 q4 = *(const float4*)&qs[t][h * 64 + d1b];
                acc[t] = fmaf(q4.x, kv[0], acc[t]);
                acc[t] = fmaf(q4.y, kv[1], acc[t]);
                acc[t] = fmaf(q4.z, kv[2], acc[t]);
                acc[t] = fmaf(q4.w, kv[3], acc[t]);
            }
        }
#pragma unroll
        for (int t = 0; t < 10; ++t)
            gpre[(size_t)(t0 + t) * 4096 + b * 512 + c] = acc[t] * gscale;
    }
}

// ---------------------------------------------------------------------------
// Fused branch kernel, LDS-staged: g-LIF + l-LIF + dwconv9-LIF + head-mix
// (wave shfl) + y0-LIF.
// ---------------------------------------------------------------------------
__global__ __launch_bounds__(256) void branch_y0_k(
    const float* __restrict__ gpre, const float* __restrict__ lpre,
    const unsigned char* __restrict__ sv, const float* __restrict__ wdw,
    const float* __restrict__ wpw, _Float16* __restrict__ sy0,
    int segLen, int warm)
{
    __shared__ __align__(16) float gb[2][8][256];        // 16 KB
    __shared__ __align__(16) float lb[2][8][256];        // 16 KB
    __shared__ __align__(16) unsigned char vbuf[2][8][256]; // 4 KB
    int tid = threadIdx.x;
    int wave = tid >> 6, lane = tid & 63;
    int gw0 = blockIdx.x * 4;          // 4 gw per block, same b (4 | 8)
    int b = gw0 >> 3;
    int dg0 = gw0 & 7;                 // 0 or 4
    int h = lane >> 3, dl = lane & 7;
    int dg = dg0 + wave;
    int c = h * 64 + dg * 8 + dl;
    int base = b * 512 + c;
    int p = h * 32 + (((wave + h) & 3) << 3) + dl;   // swizzled LDS col

    int rowS[2], gcol[2];
#pragma unroll
    for (int v = 0; v < 2; ++v) {
        int f = tid + (v << 8);
        rowS[v] = f >> 6;
        int jj = f & 63;
        int hj = jj >> 3;
        int sj = (jj >> 1) & 3;
        int wj = (sj - hj) & 3;
        gcol[v] = b * 512 + hj * 64 + dg0 * 8 + (wj << 3) + ((jj & 1) << 2);
    }

    float w9[9];
#pragma unroll
    for (int j = 0; j < 9; ++j) w9[j] = wdw[h * 9 + j];
    float w8[8];
#pragma unroll
    for (int j = 0; j < 8; ++j) w8[j] = wpw[h * 8 + j];
    int t0 = blockIdx.y * segLen;
    int twarm = (t0 - warm > 0) ? (t0 - warm) : 0;
    int tend = (t0 + segLen < TT) ? (t0 + segLen) : TT;

    auto stageGL = [&](int ct, int bi) {
#pragma unroll
        for (int v = 0; v < 2; ++v) {
            size_t ga = (size_t)(ct + rowS[v]) * 4096 + gcol[v];
            int lo = (v << 10) + (wave << 8);
            gload16f(gpre + ga, &gb[bi][0][0] + lo);
            gload16f(lpre + ga, &lb[bi][0][0] + lo);
        }
    };
    auto stageV = [&](int ct, int bi) {
#pragma unroll
        for (int v = 0; v < 2; ++v) {
            size_t ga = (size_t)(ct + rowS[v]) * 4096 + gcol[v];
            int lo = (v << 10) + (wave << 8);
            gload4b(sv + ga, &vbuf[bi][0][0] + lo);
        }
    };

    float vg = 0.f, vl = 0.f, vd = 0.f, vy = 0.f;
    float win[12];
#pragma unroll
    for (int i = 0; i < 12; ++i) {
        int tt = twarm - 4 + i;
        win[i] = (tt >= 0 && tt < TT) ? (float)sv[(size_t)tt * 4096 + base] : 0.f;
    }
    stageGL(twarm, 0);
    stageV(twarm + 8, 0);      // sv rows [twarm+8, twarm+16)
    __syncthreads();
    int cur = 0;
    for (int T0 = twarm; T0 < tend; T0 += 8) {
        if (T0 + 8 < tend) { stageGL(T0 + 8, cur ^ 1); stageV(T0 + 16, cur ^ 1); }
#pragma unroll
        for (int r = 0; r < 8; ++r) {
            int tc = T0 + r;
            if (tc >= tend) break;
            float cg = gb[cur][r][p];
            float cl = lb[cur][r][p];
            float nv = (tc + 8 < TT) ? (float)vbuf[cur][r][p] : 0.f;  // sv[tc+8]
            float x = 0.f;
#pragma unroll
            for (int q = 0; q < 9; ++q) x = fmaf(w9[q], win[q], x);
            float hd = fmaf(0.5f, vd, x);
            float sd = (hd >= 1.f) ? 1.f : 0.f;
            vd = (hd >= 1.f) ? 0.f : hd;
            float hg = fmaf(0.5f, vg, cg);
            float sg = (hg >= 1.f) ? 1.f : 0.f;
            vg = (hg >= 1.f) ? 0.f : hg;
            float hl = fmaf(0.5f, vl, cl);
            float sl = (hl >= 1.f) ? 1.f : 0.f;
            vl = (hl >= 1.f) ? 0.f : hl;
            float mix = 0.f;
#pragma unroll
            for (int h2 = 0; h2 < 8; ++h2)
                mix = fmaf(w8[h2], __shfl(sd, h2 * 8 + dl, 64), mix);
            float xy = (sg + sl) + mix;
            float hy = fmaf(0.5f, vy, xy);
            float sy = (hy >= 1.f) ? 1.f : 0.f;
            vy = (hy >= 1.f) ? 0.f : hy;
            if (tc >= t0) sy0[(size_t)tc * 4096 + base] = (_Float16)sy;
#pragma unroll
            for (int i2 = 0; i2 < 11; ++i2) win[i2] = win[i2 + 1];
            win[11] = nv;
        }
        __syncthreads();
        cur ^= 1;
    }
}

// ---------------------------------------------------------------------------
extern "C" void kernel_launch(void* const* d_in, const int* in_sizes, int n_in,
                              void* d_out, int out_size, void* d_ws, size_t ws_size,
                              hipStream_t stream)
{
    const float* x       = (const float*)d_in[0];
    const float* wq      = (const float*)d_in[1];
    const float* wk      = (const float*)d_in[2];
    const float* wv      = (const float*)d_in[3];
    const float* w_mattn = (const float*)d_in[4];
    const float* w_proj  = (const float*)d_in[5];
    const float* w_dw    = (const float*)d_in[6];
    const float* w_pw    = (const float*)d_in[7];
    const float* bn_g    = (const float*)d_in[8];
    const float* bn_b    = (const float*)d_in[9];
    float* out = (float*)d_out;
    float* ws = (float*)d_ws;

    float gs32 = (float)std::sqrt((double)(64 * 500));
    float gscale = (float)(1.0 / (double)gs32);
    float ls32 = (float)std::sqrt((double)(64 * 41));
    float lscale = (float)(1.0 / (double)ls32);
    const int M = TT * 8;   // 4000

    float* S0 = ws;
    float* S1 = ws + (size_t)NTOT;
    float* S2 = ws + 2 * (size_t)NTOT;
    float* part4   = ws + 3 * (size_t)NTOT;     // 4*262144 floats
    float* ktvBuf  = part4 + 4 * 262144;        // 262144 (unused now)
    float* colpart = ktvBuf + 262144;           // 196608 (64 chunks * 1536 * 2)
    unsigned char* spk = (unsigned char*)(colpart + 196608);
    unsigned char* sq  = spk;                    // NTOT bytes
    unsigned char* sk  = spk + (size_t)NTOT;
    unsigned char* sv  = spk + 2 * (size_t)NTOT;
    _Float16* sy0h = (_Float16*)(spk + 3 * (size_t)NTOT);   // NTOT f16
    _Float16* sy1h = (_Float16*)spk;                        // aliases sq+sk (dead after attn)
    // X splits (2-way) alias the spike region (written step 0, dead after
    // step 1; spikes first written step 2). 2*NTOT f16 = spk[0..4*NTOT).
    _Float16* X0 = (_Float16*)spk;
    _Float16* X1 = X0 + (size_t)NTOT;
    // mattn/proj weight splits (2 each): dedicated, after the 12MB envelope
    _Float16* Wm0 = (_Float16*)(spk + 6 * (size_t)NTOT);
    _Float16* Wm1 = Wm0 + 262144;
    _Float16* Wp0 = Wm1 + 262144;
    _Float16* Wp1 = Wp0 + 262144;
    // qkv weight splits (2) alias part4 (dead after step 1; part4 written step 3)
    _Float16* Wq0 = (_Float16*)part4;
    _Float16* Wq1 = Wq0 + 786432;

    // 0) splits: everything 2-way
    prep_split_k<<<3280, 256, 0, stream>>>(x, wq, wk, wv, w_mattn, w_proj,
                                           X0, X1, Wq0, Wq1,
                                           Wm0, Wm1, Wp0, Wp1);
    // 1) QKV GEMM via MFMA (768 XCD-swizzled blocks, BN=128 dbuf, 48 KB LDS)
    gemm_f16s3_k<<<768, 256, 0, stream>>>(X0, X1, Wq0, Wq1, S0, colpart, M);
    // 2) segmented BN+LIF -> uchar spikes q,k,v
    lif_seg_k<<<dim3(48, 10), 256, 0, stream>>>(S0, colpart, 1536, 64, bn_g, bn_b,
                                                nullptr, sq, nullptr, 50, 64);
    // 3) FUSED {KtV partials (256 blocks) || local attention (1024 blocks)}
    attn_fused_k<<<1280, 256, 0, stream>>>(sq, sk, sv, S1, part4, lscale);
    // 4) global apply with inline 4-way partial reduce (ktv_reduce folded in)
    gapply_t_k<<<dim3(50, 8), 256, 0, stream>>>(sq, part4, S0, gscale);       // g_pre -> S0
    // 5) fused g/l/dw LIFs + mix + y0 LIF -> fp16 spikes (LDS-staged)
    branch_y0_k<<<dim3(16, 20), 256, 0, stream>>>(S0, S1, sv, w_dw, w_pw, sy0h, 25, 64);
    // 6) mattn GEMM (MFMA, tri-buffer counted-vmcnt, W 2-split) -> S2; LIF -> sy1h
    gemm_hs3_k<<<512, 256, 0, stream>>>(sy0h, Wm0, Wm1, S2, colpart, M);
    lif_seg_k<<<dim3(16, 20), 256, 0, stream>>>(S2, colpart, 512, 64, bn_g + 1536,
                                                bn_b + 1536, nullptr, nullptr, sy1h, 25, 64);
    // 7) proj GEMM -> S0; LIF -> out (fp32)
    gemm_hs3_k<<<512, 256, 0, stream>>>(sy1h, Wp0, Wp1, S0, colpart, M);
    lif_seg_k<<<dim3(16, 20), 256, 0, stream>>>(S0, colpart, 512, 64, bn_g + 2048,
                                                bn_b + 2048, out, nullptr, nullptr, 25, 64);

    (void)in_sizes; (void)n_in; (void)out_size; (void)ws_size;
}

// Round 15
// 287.673 us; speedup vs baseline: 1.0184x; 1.0184x over previous
//
#include <hip/hip_runtime.h>
#include <cmath>

#define TT 500
#define NTOT 2048000       // T*B*C elements
#define WW 20

typedef _Float16 f16x8 __attribute__((ext_vector_type(8)));
typedef _Float16 f16x4 __attribute__((ext_vector_type(4)));
typedef float f32x4 __attribute__((ext_vector_type(4)));

#define C1SC 4.8828125e-4f          // 2^-11
#define C2SC 2.384185791015625e-7f  // 2^-22

// async global->LDS; LDS dest = wave-uniform base + lane*width
__device__ __forceinline__ void gload16(const _Float16* g, _Float16* l) {
    __builtin_amdgcn_global_load_lds(
        (const __attribute__((address_space(1))) unsigned int*)g,
        (__attribute__((address_space(3))) unsigned int*)l, 16, 0, 0);
}
__device__ __forceinline__ void gload16f(const float* g, float* l) {
    __builtin_amdgcn_global_load_lds(
        (const __attribute__((address_space(1))) unsigned int*)g,
        (__attribute__((address_space(3))) unsigned int*)l, 16, 0, 0);
}
__device__ __forceinline__ void gload4b(const unsigned char* g, unsigned char* l) {
    __builtin_amdgcn_global_load_lds(
        (const __attribute__((address_space(1))) unsigned int*)g,
        (__attribute__((address_space(3))) unsigned int*)l, 4, 0, 0);
}

// ---------------------------------------------------------------------------
// Split prep: all tensors -> 2-way scaled fp16 split (h0 + 2^-11*h1).
// ---------------------------------------------------------------------------
__global__ __launch_bounds__(256) void prep_split_k(
    const float* __restrict__ x, const float* __restrict__ wq,
    const float* __restrict__ wk, const float* __restrict__ wv,
    const float* __restrict__ wm, const float* __restrict__ wp,
    _Float16* __restrict__ X0, _Float16* __restrict__ X1,
    _Float16* __restrict__ Q0, _Float16* __restrict__ Q1,
    _Float16* __restrict__ M0, _Float16* __restrict__ M1,
    _Float16* __restrict__ P0, _Float16* __restrict__ P1)
{
    int gid = blockIdx.x * 256 + threadIdx.x;
    const float* src;
    _Float16 *d0, *d1;
    size_t si, di;
    if (gid < 512000) {
        src = x; d0 = X0; d1 = X1; si = di = (size_t)gid * 4;
    } else if (gid < 708608) {
        int g = gid - 512000;                      // 0..196607 (3 x 65536)
        int s3 = g >> 16;
        src = (s3 == 0) ? wq : ((s3 == 1) ? wk : wv);
        d0 = Q0; d1 = Q1;
        si = (size_t)(g & 65535) * 4;
        di = (size_t)g * 4;
    } else if (gid < 774144) {
        int g = gid - 708608;
        src = wm; d0 = M0; d1 = M1; si = di = (size_t)g * 4;
    } else {
        int g = gid - 774144;
        src = wp; d0 = P0; d1 = P1; si = di = (size_t)g * 4;
    }
    float4 v = *(const float4*)(src + si);
    float f[4] = {v.x, v.y, v.z, v.w};
    f16x4 a, b;
#pragma unroll
    for (int i = 0; i < 4; ++i) {
        _Float16 h0 = (_Float16)f[i];
        float r1 = f[i] - (float)h0;              // exact (Sterbenz)
        _Float16 h1 = (_Float16)(r1 * 2048.0f);   // exact pow2 scale
        a[i] = h0; b[i] = h1;
    }
    *(f16x4*)(d0 + di) = a;
    *(f16x4*)(d1 + di) = b;
}

// ---------------------------------------------------------------------------
// QKV GEMM via MFMA: x 2-split, W 2-split, 3 acc banks:
//   acc0 += a0b0 ; acc1 += a0b1 + a1b0 ; acc2 += a1b1
//   result = acc0 + 2^-11*acc1 + 2^-22*acc2   (error ~2x2^-22)
// Double-buffered gload_lds staging, BM=64,BN=128,BK=32, 4 waves (wave tile
// 32x64), grid 768, 48 KB LDS -> 3 blocks/CU.
// ---------------------------------------------------------------------------
__global__ __launch_bounds__(256) void gemm_f16s3_k(
    const _Float16* __restrict__ X0, const _Float16* __restrict__ X1,
    const _Float16* __restrict__ B0g, const _Float16* __restrict__ B1g,
    float* __restrict__ out, float* __restrict__ colpart, int M)
{
    // per buffer (12288 halfs): A0@0 A1@2048 | B0@4096 B1@8192
    __shared__ __align__(16) _Float16 sA[24576];   // 48 KB, 2 buffers
    int tid = threadIdx.x;
    int bid = blockIdx.x;
    int xcd = bid & 7;
    int j = bid >> 3;                 // 0..95
    int mblk = (xcd << 3) | (j & 7);  // 0..63
    int nblk = j >> 3;                // 0..11
    int mBase = mblk * 64;
    int nBase = nblk * 128;
    int wv = tid >> 6;
    int lane = tid & 63;
    int wr = wv >> 1, wc = wv & 1;
    int lg = lane >> 4, l16 = lane & 15;

    int subrow = lane >> 2;            // 0..15
    int s4 = lane & 3;                 // global k-chunk slot before swizzle
    int rA = (wv << 4) + subrow;       // local row 0..63
    int sl8 = (s4 ^ ((rA >> 1) & 3)) * 8;   // swizzled slot offset (halfs)
    int mA = mBase + rA; if (mA >= M) mA = 0;   // clamp; masked in epilogue
    const _Float16* gA0 = X0 + (size_t)mA * 512 + sl8;
    const _Float16* gA1 = X1 + (size_t)mA * 512 + sl8;
    const _Float16* gB00 = B0g + (size_t)(nBase + rA) * 512 + sl8;
    const _Float16* gB01 = B0g + (size_t)(nBase + 64 + rA) * 512 + sl8;
    const _Float16* gB10 = B1g + (size_t)(nBase + rA) * 512 + sl8;
    const _Float16* gB11 = B1g + (size_t)(nBase + 64 + rA) * 512 + sl8;
    int wb = wv << 9;                  // wave LDS base (halfs)
    _Float16* lA0 = sA + wb;
    _Float16* lA1 = sA + 2048 + wb;
    _Float16* lB00 = sA + 4096 + wb;
    _Float16* lB01 = sA + 6144 + wb;
    _Float16* lB10 = sA + 8192 + wb;
    _Float16* lB11 = sA + 10240 + wb;

    auto stage = [&](int kt, int off) {
        gload16(gA0 + kt, lA0 + off);
        gload16(gA1 + kt, lA1 + off);
        gload16(gB00 + kt, lB00 + off);
        gload16(gB01 + kt, lB01 + off);
        gload16(gB10 + kt, lB10 + off);
        gload16(gB11 + kt, lB11 + off);
    };

    int sd = (lg ^ ((l16 >> 1) & 3)) * 8;   // swizzled read slot (halfs)

    f32x4 acc0[2][4] = {}, acc1[2][4] = {}, acc2[2][4] = {};

    stage(0, 0);
    __syncthreads();                   // buf0 ready
    int cur = 0;
    for (int kt = 0; kt < 512; kt += 32) {
        int coff = cur * 12288;
        if (kt + 32 < 512) stage(kt + 32, 12288 - coff);   // prefetch buf^1
        f16x8 a0f[2], a1f[2];
#pragma unroll
        for (int i = 0; i < 2; ++i) {
            int off = (wr * 32 + i * 16 + l16) * 32 + sd + coff;
            a0f[i] = *(const f16x8*)&sA[off];
            a1f[i] = *(const f16x8*)&sA[2048 + off];
        }
#pragma unroll
        for (int jj = 0; jj < 4; ++jj) {
            int boff = 4096 + (wc * 64 + jj * 16 + l16) * 32 + sd + coff;
            f16x8 b0f = *(const f16x8*)&sA[boff];
            f16x8 b1f = *(const f16x8*)&sA[4096 + boff];
#pragma unroll
            for (int i = 0; i < 2; ++i) {
                acc0[i][jj] = __builtin_amdgcn_mfma_f32_16x16x32_f16(a0f[i], b0f, acc0[i][jj], 0, 0, 0);
                acc1[i][jj] = __builtin_amdgcn_mfma_f32_16x16x32_f16(a0f[i], b1f, acc1[i][jj], 0, 0, 0);
                acc1[i][jj] = __builtin_amdgcn_mfma_f32_16x16x32_f16(a1f[i], b0f, acc1[i][jj], 0, 0, 0);
                acc2[i][jj] = __builtin_amdgcn_mfma_f32_16x16x32_f16(a1f[i], b1f, acc2[i][jj], 0, 0, 0);
            }
        }
        __syncthreads();               // drains prefetch vmcnt + lgkm; swap
        cur ^= 1;
    }
#pragma unroll
    for (int i = 0; i < 2; ++i)
#pragma unroll
        for (int jj = 0; jj < 4; ++jj)
#pragma unroll
            for (int r = 0; r < 4; ++r)
                acc0[i][jj][r] = fmaf(C2SC, acc2[i][jj][r],
                                      fmaf(C1SC, acc1[i][jj][r], acc0[i][jj][r]));
    // fused per-column stats; rows >= M masked to 0.
    float* red = (float*)sA;   // [2][128][2]
#pragma unroll
    for (int jj = 0; jj < 4; ++jj) {
        float s = 0.f, q = 0.f;
#pragma unroll
        for (int i = 0; i < 2; ++i)
#pragma unroll
            for (int r = 0; r < 4; ++r) {
                int mrow = mBase + wr * 32 + i * 16 + lg * 4 + r;
                float v = (mrow < M) ? acc0[i][jj][r] : 0.f;
                s += v; q = fmaf(v, v, q);
            }
        s += __shfl_xor(s, 16, 64); s += __shfl_xor(s, 32, 64);
        q += __shfl_xor(q, 16, 64); q += __shfl_xor(q, 32, 64);
        if (lane < 16) {
            int col = wc * 64 + jj * 16 + lane;
            red[(wr * 128 + col) * 2 + 0] = s;
            red[(wr * 128 + col) * 2 + 1] = q;
        }
    }
    __syncthreads();
    if (tid < 128) {
        float ss = red[tid * 2 + 0] + red[(128 + tid) * 2 + 0];
        float qq = red[tid * 2 + 1] + red[(128 + tid) * 2 + 1];
        colpart[((size_t)mblk * 1536 + nBase + tid) * 2 + 0] = ss;
        colpart[((size_t)mblk * 1536 + nBase + tid) * 2 + 1] = qq;
    }
    int wsel = nBase >> 9;
    int col0 = nBase & 511;
    float* outp = out + (size_t)wsel * NTOT;
#pragma unroll
    for (int i = 0; i < 2; ++i) {
        int m0 = mBase + wr * 32 + i * 16 + lg * 4;
#pragma unroll
        for (int jj = 0; jj < 4; ++jj) {
            int cc = col0 + wc * 64 + jj * 16 + l16;
#pragma unroll
            for (int r = 0; r < 4; ++r) {
                int m = m0 + r;
                if (m < M) outp[(size_t)m * 512 + cc] = acc0[i][jj][r];
            }
        }
    }
}

// ---------------------------------------------------------------------------
// Spike GEMM via MFMA: A fp16 spikes (exact), W 2-split, 2 acc banks.
// TRI-buffered counted-vmcnt pipeline (vmcnt(3) steady). BM=64,BN=64,
// grid 512, 36 KB LDS.
// ---------------------------------------------------------------------------
__global__ __launch_bounds__(256) void gemm_hs3_k(
    const _Float16* __restrict__ Ah,
    const _Float16* __restrict__ B0g, const _Float16* __restrict__ B1g,
    float* __restrict__ out, float* __restrict__ colpart, int M)
{
    // per buffer (6144 halfs): A@0 B0@2048 B1@4096
    __shared__ __align__(16) _Float16 sH[18432];   // 36 KB, 3 buffers
    int tid = threadIdx.x;
    int bid = blockIdx.x;
    int xcd = bid & 7;
    int j = bid >> 3;                 // 0..63
    int mblk = (xcd << 3) | (j & 7);  // 0..63
    int nblk = j >> 3;                // 0..7
    int mBase = mblk * 64;
    int col0 = nblk * 64;
    int wv = tid >> 6;
    int lane = tid & 63;
    int wr = wv >> 1, wc = wv & 1;
    int lg = lane >> 4, l16 = lane & 15;

    int subrow = lane >> 2;
    int s4 = lane & 3;
    int rA = (wv << 4) + subrow;       // 0..63
    int sl8 = (s4 ^ ((rA >> 1) & 3)) * 8;
    int mA = mBase + rA; if (mA >= M) mA = 0;
    const _Float16* gA  = Ah  + (size_t)mA * 512 + sl8;
    const _Float16* gB0 = B0g + (size_t)(col0 + rA) * 512 + sl8;
    const _Float16* gB1 = B1g + (size_t)(col0 + rA) * 512 + sl8;
    int wb = wv << 9;

    auto stage = [&](int kt, int off) {
        gload16(gA + kt, sH + off + wb);
        gload16(gB0 + kt, sH + off + 2048 + wb);
        gload16(gB1 + kt, sH + off + 4096 + wb);
    };

    int sd = (lg ^ ((l16 >> 1) & 3)) * 8;

    f32x4 acc0[2][2] = {}, acc1[2][2] = {};

    auto compute = [&](int coff) {
        f16x8 af[2];
#pragma unroll
        for (int i = 0; i < 2; ++i)
            af[i] = *(const f16x8*)&sH[(wr * 32 + i * 16 + l16) * 32 + sd + coff];
#pragma unroll
        for (int jj = 0; jj < 2; ++jj) {
            int boff = 2048 + (wc * 32 + jj * 16 + l16) * 32 + sd + coff;
            f16x8 b0f = *(const f16x8*)&sH[boff];
            f16x8 b1f = *(const f16x8*)&sH[2048 + boff];
#pragma unroll
            for (int i = 0; i < 2; ++i) {
                acc0[i][jj] = __builtin_amdgcn_mfma_f32_16x16x32_f16(af[i], b0f, acc0[i][jj], 0, 0, 0);
                acc1[i][jj] = __builtin_amdgcn_mfma_f32_16x16x32_f16(af[i], b1f, acc1[i][jj], 0, 0, 0);
            }
        }
    };

    stage(0, 0);
    stage(32, 6144);
    int offC = 0, offS = 12288;
    for (int n = 0; n < 14; ++n) {
        asm volatile("s_waitcnt vmcnt(3)" ::: "memory");
        __builtin_amdgcn_s_barrier();
        stage((n + 2) * 32, offS);
        compute(offC);
        offC += 6144; if (offC == 18432) offC = 0;
        offS += 6144; if (offS == 18432) offS = 0;
    }
    asm volatile("s_waitcnt vmcnt(3)" ::: "memory");
    __builtin_amdgcn_s_barrier();
    compute(offC);
    offC += 6144; if (offC == 18432) offC = 0;
    asm volatile("s_waitcnt vmcnt(0)" ::: "memory");
    __builtin_amdgcn_s_barrier();
    compute(offC);
    __syncthreads();

#pragma unroll
    for (int i = 0; i < 2; ++i)
#pragma unroll
        for (int jj = 0; jj < 2; ++jj)
#pragma unroll
            for (int r = 0; r < 4; ++r)
                acc0[i][jj][r] = fmaf(C1SC, acc1[i][jj][r], acc0[i][jj][r]);
    float* red = (float*)sH;   // [2][64][2]
#pragma unroll
    for (int jj = 0; jj < 2; ++jj) {
        float s = 0.f, q = 0.f;
#pragma unroll
        for (int i = 0; i < 2; ++i)
#pragma unroll
            for (int r = 0; r < 4; ++r) {
                int mrow = mBase + wr * 32 + i * 16 + lg * 4 + r;
                float v = (mrow < M) ? acc0[i][jj][r] : 0.f;
                s += v; q = fmaf(v, v, q);
            }
        s += __shfl_xor(s, 16, 64); s += __shfl_xor(s, 32, 64);
        q += __shfl_xor(q, 16, 64); q += __shfl_xor(q, 32, 64);
        if (lane < 16) {
            int col = wc * 32 + jj * 16 + lane;
            red[(wr * 64 + col) * 2 + 0] = s;
            red[(wr * 64 + col) * 2 + 1] = q;
        }
    }
    __syncthreads();
    if (tid < 64) {
        float ss = red[tid * 2 + 0] + red[(64 + tid) * 2 + 0];
        float qq = red[tid * 2 + 1] + red[(64 + tid) * 2 + 1];
        colpart[((size_t)mblk * 512 + col0 + tid) * 2 + 0] = ss;
        colpart[((size_t)mblk * 512 + col0 + tid) * 2 + 1] = qq;
    }
#pragma unroll
    for (int i = 0; i < 2; ++i) {
        int m0 = mBase + wr * 32 + i * 16 + lg * 4;
#pragma unroll
        for (int jj = 0; jj < 2; ++jj) {
            int cc = col0 + wc * 32 + jj * 16 + l16;
#pragma unroll
            for (int r = 0; r < 4; ++r) {
                int m = m0 + r;
                if (m < M) out[(size_t)m * 512 + cc] = acc0[i][jj][r];
            }
        }
    }
}

// ---------------------------------------------------------------------------
// Time-segmented BN+LIF with INLINE stats finalize (f64, identical math).
// ---------------------------------------------------------------------------
__global__ __launch_bounds__(256) void lif_seg_k(
    const float* __restrict__ pre, const float* __restrict__ colpart, int CT, int chunks,
    const float* __restrict__ gamma, const float* __restrict__ beta,
    float* __restrict__ outF, unsigned char* __restrict__ outB,
    _Float16* __restrict__ outH, int segLen, int warm)
{
    int gid = blockIdx.x * 256 + threadIdx.x;
    int tensor = gid >> 12;
    int bc = gid & 4095;
    int ch = (tensor << 9) | (bc & 511);
    double s = 0.0, s2 = 0.0;
    for (int k = 0; k < chunks; ++k) {
        s  += (double)colpart[((size_t)k * CT + ch) * 2 + 0];
        s2 += (double)colpart[((size_t)k * CT + ch) * 2 + 1];
    }
    double mean = s / 4000.0;
    double var = s2 / 4000.0 - mean * mean;
    double scd = (double)gamma[ch] / sqrt(var + 1e-5);
    float sc = (float)scd;
    float sh = (float)((double)beta[ch] - mean * scd);
    const float* q0 = pre + (size_t)tensor * NTOT + bc;
    float* oF = outF ? outF + (size_t)tensor * NTOT + bc : nullptr;
    unsigned char* oB = outB ? outB + (size_t)tensor * NTOT + bc : nullptr;
    _Float16* oH = outH ? outH + (size_t)tensor * NTOT + bc : nullptr;
    int t0 = blockIdx.y * segLen;
    int twarm = (t0 - warm > 0) ? (t0 - warm) : 0;
    int tend = (t0 + segLen < TT) ? (t0 + segLen) : TT;
    float v = 0.f;
    float b0[8];
#pragma unroll
    for (int j = 0; j < 8; ++j) {
        int tt = twarm + j;
        b0[j] = (tt < tend) ? q0[(size_t)tt * 4096] : 0.f;
    }
    for (int t = twarm; t < tend; t += 8) {
        float n0[8];
#pragma unroll
        for (int j = 0; j < 8; ++j) {
            int tt = t + 8 + j;
            n0[j] = (tt < tend) ? q0[(size_t)tt * 4096] : 0.f;
        }
#pragma unroll
        for (int j = 0; j < 8; ++j) {
            int tc = t + j;
            if (tc >= tend) break;
            float bnx = fmaf(b0[j], sc, sh);
            float h = fmaf(0.5f, v, bnx);
            float sp = (h >= 1.f) ? 1.f : 0.f;
            v = (h >= 1.f) ? 0.f : h;
            if (tc >= t0) {
                if (oB)      oB[(size_t)tc * 4096] = (unsigned char)sp;
                else if (oH) oH[(size_t)tc * 4096] = (_Float16)sp;
                else         oF[(size_t)tc * 4096] = sp;
            }
        }
#pragma unroll
        for (int j = 0; j < 8; ++j) b0[j] = n0[j];
    }
}

// ---------------------------------------------------------------------------
// FUSED attention kernel: blocks 0..255 = KtV partials; 256..1279 = local
// banded attention. Bodies byte-identical; shared 57 KB LDS arena.
// ---------------------------------------------------------------------------
__global__ __launch_bounds__(256) void attn_fused_k(
    const unsigned char* __restrict__ qspk, const unsigned char* __restrict__ kspk,
    const unsigned char* __restrict__ vspk, float* __restrict__ lpre,
    float* __restrict__ part, float lscale)
{
    __shared__ __align__(16) float smem[14272];   // 57,088 B arena
    int tid = threadIdx.x;
    int bid = blockIdx.x;

    if (bid < 256) {
        // ---------------- ktv_part path ----------------
        float (*kb)[64] = (float(*)[64])smem;          // [16][64]
        float (*vb)[64] = (float(*)[64])(smem + 1024); // [16][64]
        int bh = bid & 63;
        int seg = bid >> 6;
        int t0p = seg * 125, t1p = t0p + 125;
        int b = bh >> 3, h = bh & 7;
        int d1b = (tid >> 4) * 4, d2b = (tid & 15) * 4;
        size_t cb = (size_t)b * 512 + h * 64;
        int sRow = tid >> 4;
        int sD = (tid & 15) * 4;
        float acc[4][4] = {};
        uchar4 pk, pv;
        auto preload = [&](int tt) {
            int t = tt + sRow;
            if (t < t1p) {
                pk = *(const uchar4*)(kspk + (size_t)t * 4096 + cb + sD);
                pv = *(const uchar4*)(vspk + (size_t)t * 4096 + cb + sD);
            } else {
                pk = make_uchar4(0, 0, 0, 0); pv = make_uchar4(0, 0, 0, 0);
            }
        };
        preload(t0p);
        for (int tt = t0p; tt < t1p; tt += 16) {
            __syncthreads();
            kb[sRow][sD + 0] = (float)pk.x; kb[sRow][sD + 1] = (float)pk.y;
            kb[sRow][sD + 2] = (float)pk.z; kb[sRow][sD + 3] = (float)pk.w;
            vb[sRow][sD + 0] = (float)pv.x; vb[sRow][sD + 1] = (float)pv.y;
            vb[sRow][sD + 2] = (float)pv.z; vb[sRow][sD + 3] = (float)pv.w;
            __syncthreads();
            preload(tt + 16);
#pragma unroll
            for (int tl = 0; tl < 16; ++tl) {
                float4 k4 = *(const float4*)&kb[tl][d1b];
                float4 v4 = *(const float4*)&vb[tl][d2b];
                float ka[4] = {k4.x, k4.y, k4.z, k4.w};
                float va[4] = {v4.x, v4.y, v4.z, v4.w};
#pragma unroll
                for (int i = 0; i < 4; ++i)
#pragma unroll
                    for (int j2 = 0; j2 < 4; ++j2)
                        acc[i][j2] = fmaf(ka[i], va[j2], acc[i][j2]);
            }
        }
        size_t ob = ((size_t)seg * 64 + bh) * 4096;
#pragma unroll
        for (int i = 0; i < 4; ++i)
            *(float4*)(part + ob + (size_t)(d1b + i) * 64 + d2b) =
                make_float4(acc[i][0], acc[i][1], acc[i][2], acc[i][3]);
        return;
    }

    // ---------------- local_k path ----------------
    int lb = bid - 256;
    int t0 = (lb >> 6) * 32;
    int bh = lb & 63;
    float (*qs)[68] = (float(*)[68])smem;            // [32][68]
    float (*ks)[68] = (float(*)[68])(smem + 2176);   // [72][68]
    float (*vs)[68] = (float(*)[68])(smem + 7072);   // [72][68]
    float (*sm)[72] = (float(*)[72])(smem + 11968);  // [32][72]
    int b = bh >> 3, h = bh & 7;
    size_t cb = (size_t)b * 512 + h * 64;

    for (int i = tid; i < 512; i += 256) {
        int r = i >> 4, d4 = (i & 15) * 4;
        int t = t0 + r;
        if (t < TT) {
            uchar4 u = *(const uchar4*)(qspk + (size_t)t * 4096 + cb + d4);
            qs[r][d4 + 0] = (float)u.x; qs[r][d4 + 1] = (float)u.y;
            qs[r][d4 + 2] = (float)u.z; qs[r][d4 + 3] = (float)u.w;
        } else {
            qs[r][d4 + 0] = 0.f; qs[r][d4 + 1] = 0.f; qs[r][d4 + 2] = 0.f; qs[r][d4 + 3] = 0.f;
        }
    }
    for (int i = tid; i < 1152; i += 256) {
        int r = i >> 4, d4 = (i & 15) * 4;
        int u_ = t0 - WW + r;
        if (u_ >= 0 && u_ < TT) {
            uchar4 uk = *(const uchar4*)(kspk + (size_t)u_ * 4096 + cb + d4);
            uchar4 uv = *(const uchar4*)(vspk + (size_t)u_ * 4096 + cb + d4);
            ks[r][d4 + 0] = (float)uk.x; ks[r][d4 + 1] = (float)uk.y;
            ks[r][d4 + 2] = (float)uk.z; ks[r][d4 + 3] = (float)uk.w;
            vs[r][d4 + 0] = (float)uv.x; vs[r][d4 + 1] = (float)uv.y;
            vs[r][d4 + 2] = (float)uv.z; vs[r][d4 + 3] = (float)uv.w;
        } else {
            ks[r][d4 + 0] = 0.f; ks[r][d4 + 1] = 0.f; ks[r][d4 + 2] = 0.f; ks[r][d4 + 3] = 0.f;
            vs[r][d4 + 0] = 0.f; vs[r][d4 + 1] = 0.f; vs[r][d4 + 2] = 0.f; vs[r][d4 + 3] = 0.f;
        }
    }
    __syncthreads();

    int tA = tid >> 3;
    int ug = tid & 7;
    float4 qreg[16];
#pragma unroll
    for (int i = 0; i < 16; ++i) qreg[i] = *(const float4*)&qs[tA][i * 4];
#pragma unroll
    for (int ui = 0; ui < 9; ++ui) {
        int u = ug + ui * 8;
        float acc = 0.f;
#pragma unroll
        for (int i = 0; i < 16; ++i) {
            float4 k4 = *(const float4*)&ks[u][i * 4];
            acc = fmaf(qreg[i].x, k4.x, acc);
            acc = fmaf(qreg[i].y, k4.y, acc);
            acc = fmaf(qreg[i].z, k4.z, acc);
            acc = fmaf(qreg[i].w, k4.w, acc);
        }
        sm[tA][u] = acc;
    }
    __syncthreads();

#pragma unroll
    for (int oi = 0; oi < 2; ++oi) {
        int idx = tid + oi * 256;
        int t = idx >> 4;
        int dg = (idx & 15) * 4;
        float4 acc = make_float4(0.f, 0.f, 0.f, 0.f);
        for (int o = 0; o < 41; ++o) {
            int u = t + o;
            float s = sm[t][u];
            float4 v4 = *(const float4*)&vs[u][dg];
            acc.x = fmaf(s, v4.x, acc.x);
            acc.y = fmaf(s, v4.y, acc.y);
            acc.z = fmaf(s, v4.z, acc.z);
            acc.w = fmaf(s, v4.w, acc.w);
        }
        int tg = t0 + t;
        if (tg < TT) {
            acc.x *= lscale; acc.y *= lscale; acc.z *= lscale; acc.w *= lscale;
            *(float4*)(lpre + (size_t)tg * 4096 + cb + dg) = acc;
        }
    }
}

__global__ __launch_bounds__(256) void ktv_reduce_k(
    const float* __restrict__ part, float* __restrict__ ktv)
{
    int i4 = (blockIdx.x * 256 + threadIdx.x) * 4;
    float4 a = *(const float4*)(part + i4);
    float4 b = *(const float4*)(part + 262144 + i4);
    float4 c = *(const float4*)(part + 2 * 262144 + i4);
    float4 d = *(const float4*)(part + 3 * 262144 + i4);
    *(float4*)(ktv + i4) = make_float4(((a.x + b.x) + c.x) + d.x,
                                       ((a.y + b.y) + c.y) + d.y,
                                       ((a.z + b.z) + c.z) + d.z,
                                       ((a.w + b.w) + c.w) + d.w);
}

// ---------------------------------------------------------------------------
// Global attention apply, t-tiled x10, float4 qs reads.
// ---------------------------------------------------------------------------
__global__ __launch_bounds__(256) void gapply_t_k(
    const unsigned char* __restrict__ sq, const float* __restrict__ ktv,
    float* __restrict__ gpre, float gscale)
{
    __shared__ __align__(16) float qs[10][512];
    int tid = threadIdx.x;
    int t0 = blockIdx.x * 10;
    int b = blockIdx.y;
    for (int i = tid; i < 1280; i += 256) {
        int t = i >> 7;
        int c4 = (i & 127) * 4;
        uchar4 u = *(const uchar4*)(sq + (size_t)(t0 + t) * 4096 + b * 512 + c4);
        qs[t][c4 + 0] = (float)u.x; qs[t][c4 + 1] = (float)u.y;
        qs[t][c4 + 2] = (float)u.z; qs[t][c4 + 3] = (float)u.w;
    }
    __syncthreads();
#pragma unroll
    for (int half = 0; half < 2; ++half) {
        int c = tid + half * 256;
        int h = c >> 6, dcol = c & 63;
        const float* kt = ktv + ((size_t)(b * 8 + h) * 64) * 64 + dcol;
        float acc[10] = {};
        for (int d1b = 0; d1b < 64; d1b += 4) {
            float kv0 = kt[(size_t)(d1b + 0) * 64];
            float kv1 = kt[(size_t)(d1b + 1) * 64];
            float kv2 = kt[(size_t)(d1b + 2) * 64];
            float kv3 = kt[(size_t)(d1b + 3) * 64];
#pragma unroll
            for (int t = 0; t < 10; ++t) {
                float4 q4 = *(const float4*)&qs[t][h * 64 + d1b];
                acc[t] = fmaf(q4.x, kv0, acc[t]);
                acc[t] = fmaf(q4.y, kv1, acc[t]);
                acc[t] = fmaf(q4.z, kv2, acc[t]);
                acc[t] = fmaf(q4.w, kv3, acc[t]);
            }
        }
#pragma unroll
        for (int t = 0; t < 10; ++t)
            gpre[(size_t)(t0 + t) * 4096 + b * 512 + c] = acc[t] * gscale;
    }
}

// ---------------------------------------------------------------------------
// Fused branch kernel, LDS-staged: g-LIF + l-LIF + dwconv9-LIF + head-mix
// (wave shfl) + y0-LIF.
// ---------------------------------------------------------------------------
__global__ __launch_bounds__(256) void branch_y0_k(
    const float* __restrict__ gpre, const float* __restrict__ lpre,
    const unsigned char* __restrict__ sv, const float* __restrict__ wdw,
    const float* __restrict__ wpw, _Float16* __restrict__ sy0,
    int segLen, int warm)
{
    __shared__ __align__(16) float gb[2][8][256];        // 16 KB
    __shared__ __align__(16) float lb[2][8][256];        // 16 KB
    __shared__ __align__(16) unsigned char vbuf[2][8][256]; // 4 KB
    int tid = threadIdx.x;
    int wave = tid >> 6, lane = tid & 63;
    int gw0 = blockIdx.x * 4;          // 4 gw per block, same b (4 | 8)
    int b = gw0 >> 3;
    int dg0 = gw0 & 7;                 // 0 or 4
    int h = lane >> 3, dl = lane & 7;
    int dg = dg0 + wave;
    int c = h * 64 + dg * 8 + dl;
    int base = b * 512 + c;
    int p = h * 32 + (((wave + h) & 3) << 3) + dl;   // swizzled LDS col

    int rowS[2], gcol[2];
#pragma unroll
    for (int v = 0; v < 2; ++v) {
        int f = tid + (v << 8);
        rowS[v] = f >> 6;
        int jj = f & 63;
        int hj = jj >> 3;
        int sj = (jj >> 1) & 3;
        int wj = (sj - hj) & 3;
        gcol[v] = b * 512 + hj * 64 + dg0 * 8 + (wj << 3) + ((jj & 1) << 2);
    }

    float w9[9];
#pragma unroll
    for (int j = 0; j < 9; ++j) w9[j] = wdw[h * 9 + j];
    float w8[8];
#pragma unroll
    for (int j = 0; j < 8; ++j) w8[j] = wpw[h * 8 + j];
    int t0 = blockIdx.y * segLen;
    int twarm = (t0 - warm > 0) ? (t0 - warm) : 0;
    int tend = (t0 + segLen < TT) ? (t0 + segLen) : TT;

    auto stageGL = [&](int ct, int bi) {
#pragma unroll
        for (int v = 0; v < 2; ++v) {
            size_t ga = (size_t)(ct + rowS[v]) * 4096 + gcol[v];
            int lo = (v << 10) + (wave << 8);
            gload16f(gpre + ga, &gb[bi][0][0] + lo);
            gload16f(lpre + ga, &lb[bi][0][0] + lo);
        }
    };
    auto stageV = [&](int ct, int bi) {
#pragma unroll
        for (int v = 0; v < 2; ++v) {
            size_t ga = (size_t)(ct + rowS[v]) * 4096 + gcol[v];
            int lo = (v << 10) + (wave << 8);
            gload4b(sv + ga, &vbuf[bi][0][0] + lo);
        }
    };

    float vg = 0.f, vl = 0.f, vd = 0.f, vy = 0.f;
    float win[12];
#pragma unroll
    for (int i = 0; i < 12; ++i) {
        int tt = twarm - 4 + i;
        win[i] = (tt >= 0 && tt < TT) ? (float)sv[(size_t)tt * 4096 + base] : 0.f;
    }
    stageGL(twarm, 0);
    stageV(twarm + 8, 0);      // sv rows [twarm+8, twarm+16)
    __syncthreads();
    int cur = 0;
    for (int T0 = twarm; T0 < tend; T0 += 8) {
        if (T0 + 8 < tend) { stageGL(T0 + 8, cur ^ 1); stageV(T0 + 16, cur ^ 1); }
#pragma unroll
        for (int r = 0; r < 8; ++r) {
            int tc = T0 + r;
            if (tc >= tend) break;
            float cg = gb[cur][r][p];
            float cl = lb[cur][r][p];
            float nv = (tc + 8 < TT) ? (float)vbuf[cur][r][p] : 0.f;  // sv[tc+8]
            float x = 0.f;
#pragma unroll
            for (int q = 0; q < 9; ++q) x = fmaf(w9[q], win[q], x);
            float hd = fmaf(0.5f, vd, x);
            float sd = (hd >= 1.f) ? 1.f : 0.f;
            vd = (hd >= 1.f) ? 0.f : hd;
            float hg = fmaf(0.5f, vg, cg);
            float sg = (hg >= 1.f) ? 1.f : 0.f;
            vg = (hg >= 1.f) ? 0.f : hg;
            float hl = fmaf(0.5f, vl, cl);
            float sl = (hl >= 1.f) ? 1.f : 0.f;
            vl = (hl >= 1.f) ? 0.f : hl;
            float mix = 0.f;
#pragma unroll
            for (int h2 = 0; h2 < 8; ++h2)
                mix = fmaf(w8[h2], __shfl(sd, h2 * 8 + dl, 64), mix);
            float xy = (sg + sl) + mix;
            float hy = fmaf(0.5f, vy, xy);
            float sy = (hy >= 1.f) ? 1.f : 0.f;
            vy = (hy >= 1.f) ? 0.f : hy;
            if (tc >= t0) sy0[(size_t)tc * 4096 + base] = (_Float16)sy;
#pragma unroll
            for (int i2 = 0; i2 < 11; ++i2) win[i2] = win[i2 + 1];
            win[11] = nv;
        }
        __syncthreads();
        cur ^= 1;
    }
}

// ---------------------------------------------------------------------------
extern "C" void kernel_launch(void* const* d_in, const int* in_sizes, int n_in,
                              void* d_out, int out_size, void* d_ws, size_t ws_size,
                              hipStream_t stream)
{
    const float* x       = (const float*)d_in[0];
    const float* wq      = (const float*)d_in[1];
    const float* wk      = (const float*)d_in[2];
    const float* wv      = (const float*)d_in[3];
    const float* w_mattn = (const float*)d_in[4];
    const float* w_proj  = (const float*)d_in[5];
    const float* w_dw    = (const float*)d_in[6];
    const float* w_pw    = (const float*)d_in[7];
    const float* bn_g    = (const float*)d_in[8];
    const float* bn_b    = (const float*)d_in[9];
    float* out = (float*)d_out;
    float* ws = (float*)d_ws;

    float gs32 = (float)std::sqrt((double)(64 * 500));
    float gscale = (float)(1.0 / (double)gs32);
    float ls32 = (float)std::sqrt((double)(64 * 41));
    float lscale = (float)(1.0 / (double)ls32);
    const int M = TT * 8;   // 4000

    float* S0 = ws;
    float* S1 = ws + (size_t)NTOT;
    float* S2 = ws + 2 * (size_t)NTOT;
    float* part4   = ws + 3 * (size_t)NTOT;     // 4*262144 floats
    float* ktvBuf  = part4 + 4 * 262144;        // 262144
    float* colpart = ktvBuf + 262144;           // 196608 (64 chunks * 1536 * 2)
    unsigned char* spk = (unsigned char*)(colpart + 196608);
    unsigned char* sq  = spk;                    // NTOT bytes
    unsigned char* sk  = spk + (size_t)NTOT;
    unsigned char* sv  = spk + 2 * (size_t)NTOT;
    _Float16* sy0h = (_Float16*)(spk + 3 * (size_t)NTOT);   // NTOT f16
    _Float16* sy1h = (_Float16*)spk;                        // aliases sq+sk (dead after attn)
    // X splits (2-way) alias the spike region (written step 0, dead after
    // step 1; spikes first written step 2). 2*NTOT f16 = spk[0..4*NTOT).
    _Float16* X0 = (_Float16*)spk;
    _Float16* X1 = X0 + (size_t)NTOT;
    // mattn/proj weight splits (2 each): dedicated, after the 12MB envelope
    _Float16* Wm0 = (_Float16*)(spk + 6 * (size_t)NTOT);
    _Float16* Wm1 = Wm0 + 262144;
    _Float16* Wp0 = Wm1 + 262144;
    _Float16* Wp1 = Wp0 + 262144;
    // qkv weight splits (2) alias part4 (dead after step 1; part4 written step 3)
    _Float16* Wq0 = (_Float16*)part4;
    _Float16* Wq1 = Wq0 + 786432;

    // 0) splits: everything 2-way
    prep_split_k<<<3280, 256, 0, stream>>>(x, wq, wk, wv, w_mattn, w_proj,
                                           X0, X1, Wq0, Wq1,
                                           Wm0, Wm1, Wp0, Wp1);
    // 1) QKV GEMM via MFMA (768 XCD-swizzled blocks, BN=128 dbuf, 48 KB LDS)
    gemm_f16s3_k<<<768, 256, 0, stream>>>(X0, X1, Wq0, Wq1, S0, colpart, M);
    // 2) segmented BN+LIF -> uchar spikes q,k,v
    lif_seg_k<<<dim3(48, 10), 256, 0, stream>>>(S0, colpart, 1536, 64, bn_g, bn_b,
                                                nullptr, sq, nullptr, 50, 64);
    // 3) FUSED {KtV partials (256 blocks) || local attention (1024 blocks)}
    attn_fused_k<<<1280, 256, 0, stream>>>(sq, sk, sv, S1, part4, lscale);
    ktv_reduce_k<<<256, 256, 0, stream>>>(part4, ktvBuf);
    gapply_t_k<<<dim3(50, 8), 256, 0, stream>>>(sq, ktvBuf, S0, gscale);      // g_pre -> S0
    // 4) fused g/l/dw LIFs + mix + y0 LIF -> fp16 spikes (LDS-staged)
    branch_y0_k<<<dim3(16, 20), 256, 0, stream>>>(S0, S1, sv, w_dw, w_pw, sy0h, 25, 64);
    // 5) mattn GEMM (MFMA, tri-buffer counted-vmcnt, W 2-split) -> S2; LIF -> sy1h
    gemm_hs3_k<<<512, 256, 0, stream>>>(sy0h, Wm0, Wm1, S2, colpart, M);
    lif_seg_k<<<dim3(16, 20), 256, 0, stream>>>(S2, colpart, 512, 64, bn_g + 1536,
                                                bn_b + 1536, nullptr, nullptr, sy1h, 25, 64);
    // 6) proj GEMM -> S0; LIF -> out (fp32)
    gemm_hs3_k<<<512, 256, 0, stream>>>(sy1h, Wp0, Wp1, S0, colpart, M);
    lif_seg_k<<<dim3(16, 20), 256, 0, stream>>>(S0, colpart, 512, 64, bn_g + 2048,
                                                bn_b + 2048, out, nullptr, nullptr, 25, 64);

    (void)in_sizes; (void)n_in; (void)out_size; (void)ws_size;
}